// Round 1
// baseline (507.130 us; speedup 1.0000x reference)
//
#include <hip/hip_runtime.h>
#include <hip/hip_bf16.h>

// Problem: B=65536 tokens, D=512, C=1000 classes, E=3 experts.
// out = [coarse_res (B*3) | select (B, stored as float) | output (B*1000)] fp32.

namespace {
constexpr int BTOK = 65536;
constexpr int DDIM = 512;
constexpr int CCLS = 1000;
constexpr float SCL = 30.0f;

typedef short v8s __attribute__((ext_vector_type(8)));
typedef float v4f __attribute__((ext_vector_type(4)));

__device__ __forceinline__ unsigned short f2bf(float x) {
  __hip_bfloat16 h = __float2bfloat16(x);
  return __builtin_bit_cast(unsigned short, h);
}

__device__ __forceinline__ void async16(const void* g, void* l) {
  __builtin_amdgcn_global_load_lds(
      (const __attribute__((address_space(1))) unsigned int*)g,
      (__attribute__((address_space(3))) unsigned int*)l, 16, 0, 0);
}
}  // namespace

// ---------------- kernel 0: normalize weights ----------------
// grid = 3003 blocks (3 coarse rows + 3000 fine rows), 256 threads.
// fp64 norm kept: per-row scaling of cw rows shifts coarse dots differently
// per expert -> argmax-relevant. Cheap kernel; don't touch correctness.
__global__ __launch_bounds__(256) void k_norm_w(
    const float* __restrict__ wc, const float* __restrict__ wf0,
    const float* __restrict__ wf1, const float* __restrict__ wf2,
    float* __restrict__ cw_out, unsigned short* __restrict__ fw_out,
    int* __restrict__ counters) {
  int r = blockIdx.x;
  int t = threadIdx.x;
  if (r == 0 && t < 4) counters[t] = 0;  // zero expert counters every launch
  const float* src;
  if (r < 3) {
    src = wc + r * DDIM;
  } else {
    int rr = r - 3;
    const float* b = (rr < CCLS) ? wf0 : (rr < 2 * CCLS ? wf1 : wf2);
    src = b + (size_t)(rr % CCLS) * DDIM;
  }
  float2 v = ((const float2*)src)[t];  // elements 2t, 2t+1
  double ss = (double)v.x * v.x + (double)v.y * v.y;
  #pragma unroll
  for (int o = 32; o > 0; o >>= 1) ss += __shfl_xor(ss, o, 64);
  __shared__ double part[4];
  int w = t >> 6, l = t & 63;
  if (l == 0) part[w] = ss;
  __syncthreads();
  double tot = part[0] + part[1] + part[2] + part[3];
  float nf = fmaxf((float)sqrt(tot), 1e-12f);
  float a = v.x / nf, b2 = v.y / nf;
  if (r < 3) {
    cw_out[r * DDIM + 2 * t] = a;
    cw_out[r * DDIM + 2 * t + 1] = b2;
  } else {
    int rr = r - 3;
    ushort2 o2;
    o2.x = f2bf(a);
    o2.y = f2bf(b2);
    ((ushort2*)fw_out)[(size_t)rr * (DDIM / 2) + t] = o2;
  }
}

// ---------------- kernel A: per-token norm + coarse + argmax ----------------
// one wave per token; grid 16384 x 256.
__global__ __launch_bounds__(256) void k_token(
    const float* __restrict__ x, const float* __restrict__ cw,
    unsigned short* __restrict__ abf, float* __restrict__ coarse_out,
    float* __restrict__ sel_out, int* __restrict__ sel_ws) {
  int w = threadIdx.x >> 6, l = threadIdx.x & 63;
  int tok = blockIdx.x * 4 + w;
  const float4* xr = (const float4*)(x + (size_t)tok * DDIM);
  float4 x0 = xr[l];
  float4 x1 = xr[l + 64];
  // fp32 norm: a single scale factor common to all 3 coarse dots -> cannot
  // change the argmax; output error negligible vs bf16 rounding.
  float ssf = x0.x * x0.x + x0.y * x0.y + x0.z * x0.z + x0.w * x0.w +
              x1.x * x1.x + x1.y * x1.y + x1.z * x1.z + x1.w * x1.w;
  #pragma unroll
  for (int o = 32; o > 0; o >>= 1) ssf += __shfl_xor(ssf, o, 64);
  float nf = fmaxf(sqrtf(ssf), 1e-12f);
  float inv = 1.0f / nf;
  float nv[8];
  nv[0] = x0.x * inv; nv[1] = x0.y * inv; nv[2] = x0.z * inv; nv[3] = x0.w * inv;
  nv[4] = x1.x * inv; nv[5] = x1.y * inv; nv[6] = x1.z * inv; nv[7] = x1.w * inv;

  // coarse dots in fp64: argmax is compared exactly downstream.
  double dot[3];
  #pragma unroll
  for (int e = 0; e < 3; ++e) {
    const float4* ce = (const float4*)(cw + e * DDIM);
    float4 c0 = ce[l];
    float4 c1 = ce[l + 64];
    dot[e] = (double)nv[0] * c0.x + (double)nv[1] * c0.y +
             (double)nv[2] * c0.z + (double)nv[3] * c0.w +
             (double)nv[4] * c1.x + (double)nv[5] * c1.y +
             (double)nv[6] * c1.z + (double)nv[7] * c1.w;
  }
  #pragma unroll
  for (int o = 32; o > 0; o >>= 1) {
    dot[0] += __shfl_xor(dot[0], o, 64);
    dot[1] += __shfl_xor(dot[1], o, 64);
    dot[2] += __shfl_xor(dot[2], o, 64);
  }

  // write normalized row as bf16
  ushort4 o0, o1;
  o0.x = f2bf(nv[0]); o0.y = f2bf(nv[1]); o0.z = f2bf(nv[2]); o0.w = f2bf(nv[3]);
  o1.x = f2bf(nv[4]); o1.y = f2bf(nv[5]); o1.z = f2bf(nv[6]); o1.w = f2bf(nv[7]);
  ushort4* ar = (ushort4*)(abf + (size_t)tok * DDIM);
  ar[l] = o0;
  ar[l + 64] = o1;

  if (l == 0) {
    float c0f = (float)dot[0] * SCL;
    float c1f = (float)dot[1] * SCL;
    float c2f = (float)dot[2] * SCL;
    int s = 0;
    float best = c0f;
    if (c1f > best) { best = c1f; s = 1; }
    if (c2f > best) { s = 2; }
    coarse_out[tok * 3 + 0] = c0f;
    coarse_out[tok * 3 + 1] = c1f;
    coarse_out[tok * 3 + 2] = c2f;
    sel_out[tok] = (float)s;
    sel_ws[tok] = s;
  }
}

// ---------------- kernel C: compact token ids per expert ----------------
__global__ __launch_bounds__(256) void k_compact(
    const int* __restrict__ sel_ws, int* __restrict__ counters,
    int* __restrict__ lists) {
  __shared__ int lc[3], lb[3];
  int t = threadIdx.x;
  if (t < 3) lc[t] = 0;
  __syncthreads();
  int tok = blockIdx.x * 256 + t;
  int s = sel_ws[tok];
  int pos = atomicAdd(&lc[s], 1);
  __syncthreads();
  if (t < 3) lb[t] = atomicAdd(&counters[t], lc[t]);
  __syncthreads();
  lists[(size_t)s * BTOK + lb[s] + pos] = tok;
}

// ---------------- kernel B: routed GEMM, gathered A, bf16 MFMA ----------------
// grid (8 n-tiles, 515 flat m-tiles), 256 threads (4 waves, 2x2 of 64x64).
//
// NEW (this round): 3-deep software pipeline at BK=32 with counted vmcnt
// (T3+T4 minimum form) instead of the old stage->full-drain->compute
// structure that exposed the full L3 gather latency every K-step.
//   - Triple-buffered LDS K-tiles (3 x 8 KiB x 2 = 48 KiB) -> keeps
//     >=3 blocks/CU (a BK=64 double buffer at 64 KiB would drop to 2,
//     the m132-style occupancy cliff).
//   - Per iteration: vmcnt(8) [oldest stage done] -> s_barrier -> ds_read
//     + 16 MFMA (setprio-wrapped) -> s_barrier -> issue stage(kt+3) into
//     the buffer just consumed. vmcnt never drains to 0 in the main loop;
//     each stage has ~2 compute iterations to cover its latency.
//   - XOR swizzle re-derived for 4-chunk rows: LDS 16B-slot s of row r
//     holds source chunk s ^ ((r>>1)&3) (applied on the gather source,
//     since global_load_lds writes linearly; same involution on read).
//     64 lanes -> 8 distinct 16B slots x 8-lane broadcast = conflict-free.
__global__ __launch_bounds__(256) void k_gemm(
    const unsigned short* __restrict__ abf, const unsigned short* __restrict__ fw,
    const int* __restrict__ counters, const int* __restrict__ lists,
    float* __restrict__ outp) {
  int c0 = counters[0], c1 = counters[1], c2 = counters[2];
  int t0 = (c0 + 127) >> 7, t1 = (c1 + 127) >> 7, t2 = (c2 + 127) >> 7;
  int y = blockIdx.y;
  int e, m0, cnt;
  if (y < t0) { e = 0; m0 = y << 7; cnt = c0; }
  else if (y < t0 + t1) { e = 1; m0 = (y - t0) << 7; cnt = c1; }
  else if (y < t0 + t1 + t2) { e = 2; m0 = (y - t0 - t1) << 7; cnt = c2; }
  else return;
  int n0 = blockIdx.x * 128;
  const int* list = lists + (size_t)e * BTOK;

  __shared__ unsigned short As[3][128 * 32];
  __shared__ unsigned short Bs[3][128 * 32];

  int t = threadIdx.x;
  int w = t >> 6;
  int l = t & 63;

  // --- staging addresses: per thread, 2 A-chunks + 2 B-chunks per stage ---
  // LDS slot index (j*256 + t): row = j*64 + (t>>2), 16B slot s = t&3.
  // Swizzle class of row r is x = (r>>1)&3; here x = (t>>3)&3 (j-invariant).
  int srow = t >> 2;
  int cA = (t & 3) ^ ((t >> 3) & 3);  // source chunk feeding slot t&3
  const unsigned short* aSrc[2];
  const unsigned short* bSrc[2];
  #pragma unroll
  for (int j = 0; j < 2; ++j) {
    int row = j * 64 + srow;
    int gm = m0 + row;
    if (gm >= cnt) gm = cnt - 1;
    int tok = list[gm];
    aSrc[j] = abf + (size_t)tok * DDIM + cA * 8;
    int cls = n0 + row;
    if (cls >= CCLS) cls = CCLS - 1;
    bSrc[j] = fw + ((size_t)e * CCLS + cls) * DDIM + cA * 8;
  }

  int wm = w & 1, wn = w >> 1;
  int quad = l >> 4, l15 = l & 15;
  // read-side swizzled slot (in shorts): want chunk=quad of row (..+l15);
  // row's swizzle class is (l15>>1)&3 (wm*64, i*16 contribute 0 mod 4 after >>1).
  int sR = (quad ^ ((l15 >> 1) & 3)) * 8;

  v4f acc[4][4] = {};

  auto stage = [&](int kt, int b) {
    int k0 = kt * 32;  // shorts
    #pragma unroll
    for (int j = 0; j < 2; ++j) {
      async16(aSrc[j] + k0, &As[b][(j * 256 + w * 64) * 8]);
      async16(bSrc[j] + k0, &Bs[b][(j * 256 + w * 64) * 8]);
    }
  };

  // prologue: fill the 3-deep pipe (12 loads/thread outstanding)
  stage(0, 0);
  stage(1, 1);
  stage(2, 2);

  #pragma unroll
  for (int kt = 0; kt < 16; ++kt) {
    // wait until the oldest stage (kt) has landed; keep the 2 younger
    // stages (4 loads each) in flight across the barrier.
    if (kt < 14)       asm volatile("s_waitcnt vmcnt(8)" ::: "memory");
    else if (kt == 14) asm volatile("s_waitcnt vmcnt(4)" ::: "memory");
    else               asm volatile("s_waitcnt vmcnt(0)" ::: "memory");
    __builtin_amdgcn_s_barrier();
    asm volatile("" ::: "memory");        // no ds_read hoists above barrier
    __builtin_amdgcn_sched_barrier(0);

    const unsigned short* Ab = As[kt % 3];
    const unsigned short* Bb = Bs[kt % 3];
    v8s af[4], bfr[4];
    #pragma unroll
    for (int i = 0; i < 4; ++i) {
      af[i]  = *(const v8s*)(Ab + (wm * 64 + i * 16 + l15) * 32 + sR);
      bfr[i] = *(const v8s*)(Bb + (wn * 64 + i * 16 + l15) * 32 + sR);
    }
    __builtin_amdgcn_s_setprio(1);
    #pragma unroll
    for (int i = 0; i < 4; ++i)
      #pragma unroll
      for (int j = 0; j < 4; ++j)
        acc[i][j] = __builtin_amdgcn_mfma_f32_16x16x32_bf16(af[i], bfr[j], acc[i][j], 0, 0, 0);
    __builtin_amdgcn_s_setprio(0);

    __builtin_amdgcn_s_barrier();          // all waves done reading buf kt%3
    asm volatile("" ::: "memory");         // no stage issue hoists above it
    __builtin_amdgcn_sched_barrier(0);
    if (kt + 3 < 16) stage(kt + 3, kt % 3);  // overwrite the consumed buffer
  }

  #pragma unroll
  for (int i = 0; i < 4; ++i) {
    #pragma unroll
    for (int r = 0; r < 4; ++r) {
      int row = wm * 64 + i * 16 + quad * 4 + r;
      int gm = m0 + row;
      if (gm >= cnt) continue;
      int tok = list[gm];
      float* orow = outp + (size_t)tok * CCLS;
      #pragma unroll
      for (int j = 0; j < 4; ++j) {
        int col = n0 + wn * 64 + j * 16 + l15;
        if (col < CCLS) orow[col] = acc[i][j][r] * SCL;
      }
    }
  }
}

extern "C" void kernel_launch(void* const* d_in, const int* in_sizes, int n_in,
                              void* d_out, int out_size, void* d_ws, size_t ws_size,
                              hipStream_t stream) {
  const float* x = (const float*)d_in[0];
  const float* wc = (const float*)d_in[1];
  const float* wf0 = (const float*)d_in[2];
  const float* wf1 = (const float*)d_in[3];
  const float* wf2 = (const float*)d_in[4];

  float* dout = (float*)d_out;
  float* coarse_out = dout;                 // B*3
  float* sel_out = dout + (size_t)BTOK * 3; // B
  float* outp = dout + (size_t)BTOK * 4;    // B*1000

  // workspace layout
  char* ws = (char*)d_ws;
  unsigned short* abf = (unsigned short*)(ws);                   // B*512*2 = 67,108,864
  unsigned short* fwn = (unsigned short*)(ws + 67108864);        // 3*1000*512*2 = 3,072,000
  float* cwn = (float*)(ws + 70180864);                          // 3*512*4 = 6,144
  int* counters = (int*)(ws + 70187008);                         // 16
  int* sel_ws = (int*)(ws + 70187264);                           // B*4
  int* lists = (int*)(ws + 70449408);                            // 3*B*4

  k_norm_w<<<3003, 256, 0, stream>>>(wc, wf0, wf1, wf2, cwn, fwn, counters);
  k_token<<<BTOK / 4, 256, 0, stream>>>(x, cwn, abf, coarse_out, sel_out, sel_ws);
  k_compact<<<BTOK / 256, 256, 0, stream>>>(sel_ws, counters, lists);
  k_gemm<<<dim3(8, 515, 1), 256, 0, stream>>>(abf, fwn, counters, lists, outp);
}

// Round 2
// 482.815 us; speedup vs baseline: 1.0504x; 1.0504x over previous
//
#include <hip/hip_runtime.h>
#include <hip/hip_bf16.h>

// Problem: B=65536 tokens, D=512, C=1000 classes, E=3 experts.
// out = [coarse_res (B*3) | select (B, stored as float) | output (B*1000)] fp32.

namespace {
constexpr int BTOK = 65536;
constexpr int DDIM = 512;
constexpr int CCLS = 1000;
constexpr float SCL = 30.0f;

typedef short v8s __attribute__((ext_vector_type(8)));
typedef float v4f __attribute__((ext_vector_type(4)));

__device__ __forceinline__ unsigned short f2bf(float x) {
  __hip_bfloat16 h = __float2bfloat16(x);
  return __builtin_bit_cast(unsigned short, h);
}

__device__ __forceinline__ void async16(const void* g, void* l) {
  __builtin_amdgcn_global_load_lds(
      (const __attribute__((address_space(1))) unsigned int*)g,
      (__attribute__((address_space(3))) unsigned int*)l, 16, 0, 0);
}
}  // namespace

// ---------------- kernel 0: normalize weights ----------------
// grid = 3003 blocks (3 coarse rows + 3000 fine rows), 256 threads.
// fp64 norm kept: per-row scaling of cw rows shifts coarse dots differently
// per expert -> argmax-relevant. Cheap kernel; don't touch correctness.
__global__ __launch_bounds__(256) void k_norm_w(
    const float* __restrict__ wc, const float* __restrict__ wf0,
    const float* __restrict__ wf1, const float* __restrict__ wf2,
    float* __restrict__ cw_out, unsigned short* __restrict__ fw_out,
    int* __restrict__ counters) {
  int r = blockIdx.x;
  int t = threadIdx.x;
  if (r == 0 && t < 4) counters[t] = 0;  // zero expert counters every launch
  const float* src;
  if (r < 3) {
    src = wc + r * DDIM;
  } else {
    int rr = r - 3;
    const float* b = (rr < CCLS) ? wf0 : (rr < 2 * CCLS ? wf1 : wf2);
    src = b + (size_t)(rr % CCLS) * DDIM;
  }
  float2 v = ((const float2*)src)[t];  // elements 2t, 2t+1
  double ss = (double)v.x * v.x + (double)v.y * v.y;
  #pragma unroll
  for (int o = 32; o > 0; o >>= 1) ss += __shfl_xor(ss, o, 64);
  __shared__ double part[4];
  int w = t >> 6, l = t & 63;
  if (l == 0) part[w] = ss;
  __syncthreads();
  double tot = part[0] + part[1] + part[2] + part[3];
  float nf = fmaxf((float)sqrt(tot), 1e-12f);
  float a = v.x / nf, b2 = v.y / nf;
  if (r < 3) {
    cw_out[r * DDIM + 2 * t] = a;
    cw_out[r * DDIM + 2 * t + 1] = b2;
  } else {
    int rr = r - 3;
    ushort2 o2;
    o2.x = f2bf(a);
    o2.y = f2bf(b2);
    ((ushort2*)fw_out)[(size_t)rr * (DDIM / 2) + t] = o2;
  }
}

// ---------------- kernel A: per-token norm + coarse + argmax ----------------
// one wave per token; grid 16384 x 256.
__global__ __launch_bounds__(256) void k_token(
    const float* __restrict__ x, const float* __restrict__ cw,
    unsigned short* __restrict__ abf, float* __restrict__ coarse_out,
    float* __restrict__ sel_out, int* __restrict__ sel_ws) {
  int w = threadIdx.x >> 6, l = threadIdx.x & 63;
  int tok = blockIdx.x * 4 + w;
  const float4* xr = (const float4*)(x + (size_t)tok * DDIM);
  float4 x0 = xr[l];
  float4 x1 = xr[l + 64];
  // fp32 norm: a single scale factor common to all 3 coarse dots -> cannot
  // change the argmax; output error negligible vs bf16 rounding.
  float ssf = x0.x * x0.x + x0.y * x0.y + x0.z * x0.z + x0.w * x0.w +
              x1.x * x1.x + x1.y * x1.y + x1.z * x1.z + x1.w * x1.w;
  #pragma unroll
  for (int o = 32; o > 0; o >>= 1) ssf += __shfl_xor(ssf, o, 64);
  float nf = fmaxf(sqrtf(ssf), 1e-12f);
  float inv = 1.0f / nf;
  float nv[8];
  nv[0] = x0.x * inv; nv[1] = x0.y * inv; nv[2] = x0.z * inv; nv[3] = x0.w * inv;
  nv[4] = x1.x * inv; nv[5] = x1.y * inv; nv[6] = x1.z * inv; nv[7] = x1.w * inv;

  // coarse dots in fp64: argmax is compared exactly downstream.
  double dot[3];
  #pragma unroll
  for (int e = 0; e < 3; ++e) {
    const float4* ce = (const float4*)(cw + e * DDIM);
    float4 c0 = ce[l];
    float4 c1 = ce[l + 64];
    dot[e] = (double)nv[0] * c0.x + (double)nv[1] * c0.y +
             (double)nv[2] * c0.z + (double)nv[3] * c0.w +
             (double)nv[4] * c1.x + (double)nv[5] * c1.y +
             (double)nv[6] * c1.z + (double)nv[7] * c1.w;
  }
  #pragma unroll
  for (int o = 32; o > 0; o >>= 1) {
    dot[0] += __shfl_xor(dot[0], o, 64);
    dot[1] += __shfl_xor(dot[1], o, 64);
    dot[2] += __shfl_xor(dot[2], o, 64);
  }

  // write normalized row as bf16
  ushort4 o0, o1;
  o0.x = f2bf(nv[0]); o0.y = f2bf(nv[1]); o0.z = f2bf(nv[2]); o0.w = f2bf(nv[3]);
  o1.x = f2bf(nv[4]); o1.y = f2bf(nv[5]); o1.z = f2bf(nv[6]); o1.w = f2bf(nv[7]);
  ushort4* ar = (ushort4*)(abf + (size_t)tok * DDIM);
  ar[l] = o0;
  ar[l + 64] = o1;

  if (l == 0) {
    float c0f = (float)dot[0] * SCL;
    float c1f = (float)dot[1] * SCL;
    float c2f = (float)dot[2] * SCL;
    int s = 0;
    float best = c0f;
    if (c1f > best) { best = c1f; s = 1; }
    if (c2f > best) { s = 2; }
    coarse_out[tok * 3 + 0] = c0f;
    coarse_out[tok * 3 + 1] = c1f;
    coarse_out[tok * 3 + 2] = c2f;
    sel_out[tok] = (float)s;
    sel_ws[tok] = s;
  }
}

// ---------------- kernel C: compact token ids per expert ----------------
__global__ __launch_bounds__(256) void k_compact(
    const int* __restrict__ sel_ws, int* __restrict__ counters,
    int* __restrict__ lists) {
  __shared__ int lc[3], lb[3];
  int t = threadIdx.x;
  if (t < 3) lc[t] = 0;
  __syncthreads();
  int tok = blockIdx.x * 256 + t;
  int s = sel_ws[tok];
  int pos = atomicAdd(&lc[s], 1);
  __syncthreads();
  if (t < 3) lb[t] = atomicAdd(&counters[t], lc[t]);
  __syncthreads();
  lists[(size_t)s * BTOK + lb[s] + pos] = tok;
}

// ---------------- kernel B: routed GEMM, gathered A, bf16 MFMA ----------------
// grid (8, 515) = 4120 blocks, 256 threads (4 waves, 2x2 of 64x64).
//
// 3-deep software pipeline at BK=32 with counted vmcnt (see round 1).
//
// NEW (this round): XCD-aware work remap (T1, bijective m204 form).
// Round-1 counters: FETCH_SIZE = 268 MB vs 70 MB distinct input -> the 8
// n-tile blocks sharing one gathered A panel dispatch consecutively and
// land on 8 DIFFERENT XCDs (private L2s), each re-fetching the panel from
// HBM/L3 (L3 thrashed by the 256 MB output stream). Remap so each XCD owns
// a contiguous chunk of m-tiles with the 8 n-tiles of each m-tile running
// back-to-back on that XCD: working set ~12 A-panels (1.5 MB) + B expert
// panels (<=1 MB) fits the 4 MB per-XCD L2. Gathers become ~200-cyc L2
// hits, which the 2-iteration-deep vmcnt pipeline CAN cover (a ~900-cyc
// HBM miss it could not).
__global__ __launch_bounds__(256) void k_gemm(
    const unsigned short* __restrict__ abf, const unsigned short* __restrict__ fw,
    const int* __restrict__ counters, const int* __restrict__ lists,
    float* __restrict__ outp) {
  // --- XCD-aware remap: hardware dispatch id fid -> work id wid ---
  // fid % 8 == XCD (empirical round-robin). nwg = 4120 = 8*515 exactly, so
  // the bijective chunk map is wid = (fid%8)*515 + fid/8. Within a chunk,
  // consecutive wids iterate n-tiles fastest (wid&7) inside one m-tile
  // (wid>>3) -> A-panel reuse is XCD-local.
  int fid = blockIdx.y * 8 + blockIdx.x;
  int wid = (fid & 7) * 515 + (fid >> 3);
  int y = wid >> 3;        // m-tile index 0..514
  int n0 = (wid & 7) << 7; // n-tile origin

  int c0 = counters[0], c1 = counters[1], c2 = counters[2];
  int t0 = (c0 + 127) >> 7, t1 = (c1 + 127) >> 7, t2 = (c2 + 127) >> 7;
  int e, m0, cnt;
  if (y < t0) { e = 0; m0 = y << 7; cnt = c0; }
  else if (y < t0 + t1) { e = 1; m0 = (y - t0) << 7; cnt = c1; }
  else if (y < t0 + t1 + t2) { e = 2; m0 = (y - t0 - t1) << 7; cnt = c2; }
  else return;
  const int* list = lists + (size_t)e * BTOK;

  __shared__ unsigned short As[3][128 * 32];
  __shared__ unsigned short Bs[3][128 * 32];

  int t = threadIdx.x;
  int w = t >> 6;
  int l = t & 63;

  // --- staging addresses: per thread, 2 A-chunks + 2 B-chunks per stage ---
  // LDS slot index (j*256 + t): row = j*64 + (t>>2), 16B slot s = t&3.
  // Swizzle class of row r is x = (r>>1)&3; here x = (t>>3)&3 (j-invariant).
  int srow = t >> 2;
  int cA = (t & 3) ^ ((t >> 3) & 3);  // source chunk feeding slot t&3
  const unsigned short* aSrc[2];
  const unsigned short* bSrc[2];
  #pragma unroll
  for (int j = 0; j < 2; ++j) {
    int row = j * 64 + srow;
    int gm = m0 + row;
    if (gm >= cnt) gm = cnt - 1;
    int tok = list[gm];
    aSrc[j] = abf + (size_t)tok * DDIM + cA * 8;
    int cls = n0 + row;
    if (cls >= CCLS) cls = CCLS - 1;
    bSrc[j] = fw + ((size_t)e * CCLS + cls) * DDIM + cA * 8;
  }

  int wm = w & 1, wn = w >> 1;
  int quad = l >> 4, l15 = l & 15;
  // read-side swizzled slot (in shorts): want chunk=quad of row (..+l15);
  // row's swizzle class is (l15>>1)&3 (wm*64, i*16 contribute 0 mod 4 after >>1).
  int sR = (quad ^ ((l15 >> 1) & 3)) * 8;

  v4f acc[4][4] = {};

  auto stage = [&](int kt, int b) {
    int k0 = kt * 32;  // shorts
    #pragma unroll
    for (int j = 0; j < 2; ++j) {
      async16(aSrc[j] + k0, &As[b][(j * 256 + w * 64) * 8]);
      async16(bSrc[j] + k0, &Bs[b][(j * 256 + w * 64) * 8]);
    }
  };

  // prologue: fill the 3-deep pipe (12 loads/thread outstanding)
  stage(0, 0);
  stage(1, 1);
  stage(2, 2);

  #pragma unroll
  for (int kt = 0; kt < 16; ++kt) {
    // wait until the oldest stage (kt) has landed; keep the 2 younger
    // stages (4 loads each) in flight across the barrier.
    if (kt < 14)       asm volatile("s_waitcnt vmcnt(8)" ::: "memory");
    else if (kt == 14) asm volatile("s_waitcnt vmcnt(4)" ::: "memory");
    else               asm volatile("s_waitcnt vmcnt(0)" ::: "memory");
    __builtin_amdgcn_s_barrier();
    asm volatile("" ::: "memory");        // no ds_read hoists above barrier
    __builtin_amdgcn_sched_barrier(0);

    const unsigned short* Ab = As[kt % 3];
    const unsigned short* Bb = Bs[kt % 3];
    v8s af[4], bfr[4];
    #pragma unroll
    for (int i = 0; i < 4; ++i) {
      af[i]  = *(const v8s*)(Ab + (wm * 64 + i * 16 + l15) * 32 + sR);
      bfr[i] = *(const v8s*)(Bb + (wn * 64 + i * 16 + l15) * 32 + sR);
    }
    __builtin_amdgcn_s_setprio(1);
    #pragma unroll
    for (int i = 0; i < 4; ++i)
      #pragma unroll
      for (int j = 0; j < 4; ++j)
        acc[i][j] = __builtin_amdgcn_mfma_f32_16x16x32_bf16(af[i], bfr[j], acc[i][j], 0, 0, 0);
    __builtin_amdgcn_s_setprio(0);

    __builtin_amdgcn_s_barrier();          // all waves done reading buf kt%3
    asm volatile("" ::: "memory");         // no stage issue hoists above it
    __builtin_amdgcn_sched_barrier(0);
    if (kt + 3 < 16) stage(kt + 3, kt % 3);  // overwrite the consumed buffer
  }

  #pragma unroll
  for (int i = 0; i < 4; ++i) {
    #pragma unroll
    for (int r = 0; r < 4; ++r) {
      int row = wm * 64 + i * 16 + quad * 4 + r;
      int gm = m0 + row;
      if (gm >= cnt) continue;
      int tok = list[gm];
      float* orow = outp + (size_t)tok * CCLS;
      #pragma unroll
      for (int j = 0; j < 4; ++j) {
        int col = n0 + wn * 64 + j * 16 + l15;
        if (col < CCLS) orow[col] = acc[i][j][r] * SCL;
      }
    }
  }
}

extern "C" void kernel_launch(void* const* d_in, const int* in_sizes, int n_in,
                              void* d_out, int out_size, void* d_ws, size_t ws_size,
                              hipStream_t stream) {
  const float* x = (const float*)d_in[0];
  const float* wc = (const float*)d_in[1];
  const float* wf0 = (const float*)d_in[2];
  const float* wf1 = (const float*)d_in[3];
  const float* wf2 = (const float*)d_in[4];

  float* dout = (float*)d_out;
  float* coarse_out = dout;                 // B*3
  float* sel_out = dout + (size_t)BTOK * 3; // B
  float* outp = dout + (size_t)BTOK * 4;    // B*1000

  // workspace layout
  char* ws = (char*)d_ws;
  unsigned short* abf = (unsigned short*)(ws);                   // B*512*2 = 67,108,864
  unsigned short* fwn = (unsigned short*)(ws + 67108864);        // 3*1000*512*2 = 3,072,000
  float* cwn = (float*)(ws + 70180864);                          // 3*512*4 = 6,144
  int* counters = (int*)(ws + 70187008);                         // 16
  int* sel_ws = (int*)(ws + 70187264);                           // B*4
  int* lists = (int*)(ws + 70449408);                            // 3*B*4

  k_norm_w<<<3003, 256, 0, stream>>>(wc, wf0, wf1, wf2, cwn, fwn, counters);
  k_token<<<BTOK / 4, 256, 0, stream>>>(x, cwn, abf, coarse_out, sel_out, sel_ws);
  k_compact<<<BTOK / 256, 256, 0, stream>>>(sel_ws, counters, lists);
  k_gemm<<<dim3(8, 515, 1), 256, 0, stream>>>(abf, fwn, counters, lists, outp);
}